// Round 1
// baseline (155.216 us; speedup 1.0000x reference)
//
#include <hip/hip_runtime.h>
#include <cstdint>
#include <cstddef>

// LogMM_19490561589867: x [8,2048,1024] f32, matrix [1024,1024] f32
// out = log(max(x @ matrix, tiny))  [8,2048,1024] f32
// Round-8: FUSE the A fp8 conversion into the GEMM (kills the 80 MiB prep
// A round-trip: read f32 -> write fp8 -> re-read fp8). GEMM now reads A f32
// directly, converts in-register (same cvt_pk_fp8_f32 RNE -> identical
// numerics, absmax 0.03125 vs threshold 0.11375), stages fp8 to LDS.
// Tile shrunk to 128x128 (acc 64 VGPR) so the f32 prefetch (64 VGPR in
// flight) keeps total <= ~210 VGPR -> 2 blocks/CU preserved.
// HBM: A 64 MiB (L2-shared x8 within XCD) + Bt 1 MiB + C 64 MiB ~= 129 MiB.
#define M_GLOB 16384
#define N_GLOB 1024
#define K_GLOB 1024

#define BM 128    // block tile rows
#define BN 128    // block tile cols (8 n-blocks share an A panel on one XCD)
#define BKF 128   // fp8 K-tile bytes: 2 MX K=64 steps per kt, 8 kt total

typedef unsigned char  u8;
typedef unsigned short u16;
typedef __attribute__((ext_vector_type(4))) float  f32x4;
typedef __attribute__((ext_vector_type(16))) float f32x16;
typedef __attribute__((ext_vector_type(4))) unsigned int  u32x4;
typedef __attribute__((ext_vector_type(2))) unsigned int  u32x2;
typedef __attribute__((ext_vector_type(8))) int  i32x8;
typedef __attribute__((ext_vector_type(8))) __bf16 bf16x8;

// truncating pack (fallback fused path — round-1 proven numerics)
static __device__ __forceinline__ unsigned pack2_bf16(float lo, float hi) {
    unsigned bl = __builtin_bit_cast(unsigned, lo);
    unsigned bh = __builtin_bit_cast(unsigned, hi);
    return (bh & 0xFFFF0000u) | (bl >> 16);
}

// 4 fp32 -> 4 fp8 e4m3 bytes (HW RNE, OCP on gfx950)
static __device__ __forceinline__ unsigned cvt4_fp8(float a, float b, float c, float d) {
    int w = __builtin_amdgcn_cvt_pk_fp8_f32(a, b, 0, false);
    w = __builtin_amdgcn_cvt_pk_fp8_f32(c, d, w, true);
    return (unsigned)w;
}

// Raw workgroup barrier: compiler memory-clobber but NO vmcnt drain — pending
// global->VGPR prefetch loads stay in flight across it (m139 pattern).
static __device__ __forceinline__ void barrier_raw() {
    asm volatile("s_barrier" ::: "memory");
}

// ---------------------------------------------------------------------------
// B-only prep: Bt_fp8[n][k] = e4m3(B[k][n]), 32x32 LDS-transposed tiles.
// 1024 blocks, ~5 MB traffic (~2 us). Same proven code as before.
// ---------------------------------------------------------------------------
__global__ __launch_bounds__(256)
void prep_b_kernel(const float* __restrict__ B, u8* __restrict__ Bt) {
    __shared__ float tile[32][33];
    const int tid = threadIdx.x;
    const int bid = (int)blockIdx.x;
    const int n0 = (bid & 31) * 32;
    const int k0 = (bid >> 5) * 32;
    const int tx = tid & 31;
    const int ty = tid >> 5;   // 0..7
#pragma unroll
    for (int i = 0; i < 32; i += 8)
        tile[ty + i][tx] = B[(size_t)(k0 + ty + i) * N_GLOB + n0 + tx];
    __syncthreads();
#pragma unroll
    for (int i = 0; i < 32; i += 8) {
        int w = __builtin_amdgcn_cvt_pk_fp8_f32(tile[tx][ty + i], 0.f, 0, false);
        Bt[(size_t)(n0 + ty + i) * K_GLOB + k0 + tx] = (u8)(w & 0xFF);
    }
}

// ---------------------------------------------------------------------------
// Fused GEMM: A f32 (converted in-register to fp8), Bt fp8 (from ws), f32 C.
//  - mfma_scale_f32_32x32x64_f8f6f4, scales 0x7F (=1.0): pure fp8 at 2x rate.
//  - Block 128x128; wave tile 64x64 = 2x2 of 32x32 (acc 64 VGPR).
//  - Pipeline: after the staging barrier, issue next tile's 16x dwordx4 f32
//    A-loads + 4x dwordx4 B-loads; run the 8 MFMAs; then convert the landed
//    f32 to fp8 (vmcnt wait sits after compute); raw s_barrier (no vmcnt
//    drain) so stores at the next top consume converted regs.
//  - LDS XOR swizzle invariant (round-3 measured zero-conflict): 16B chunk
//    position p of row r holds global chunk c = p ^ (r&7), rows are 128 B.
//    A writer: thread covers dword-pair (kc,kc+1), kc=2*(tid&15):
//    chunk = kc>>2, pos = (kc>>2)^(r&7), dword offset 8*(tid&1). b64 writes,
//    conflict-free (4 rows x full-row coverage per wave inst).
//  - Epilogue: 4 chunks of 32 rows staged via LDS (stride 132) ->
//    coalesced nontemporal f32x4 stores (proven WRITE_SIZE == ideal).
// ---------------------------------------------------------------------------
__global__ __launch_bounds__(256, 2)
void gemm_fused_kernel(const float* __restrict__ A,
                       const u8* __restrict__ Bt,
                       float* __restrict__ C)
{
    // As: 128x128 fp8 = 16 KB @0 ; Bs: 128x128 fp8 = 16 KB @16384.
    // Epilogue reuses first 16896 B as Cs (32 rows x 132 f32).
    __shared__ __attribute__((aligned(16))) char smem[32768];
    float* Cs = (float*)smem;

    const int tid  = threadIdx.x;
    const int wave = tid >> 6;
    const int lane = tid & 63;
    const int wr   = wave >> 1;     // wave row: 64 rows each
    const int wc   = wave & 1;      // wave col: 64 cols each
    const int l32  = lane & 31;
    const int half = lane >> 5;     // k-half selector of the MFMA operand

    // XCD-contiguous swizzle: 8 blocks sharing an A panel land on one XCD.
    const int b    = (int)blockIdx.x;     // 0..1023
    const int xcd  = b & 7;
    const int idx  = b >> 3;              // 0..127
    const int m0   = (xcd * 16 + (idx >> 3)) * BM;
    const int n0   = (idx & 7) * BN;

    // ---- B staging map (identical to proven kernel): slot covers 8 rows.
    const int srow = lane >> 3;                  // 0..7
    const int sp   = lane & 7;                   // LDS chunk position
    const int sc   = sp ^ srow;                  // swizzled global 16B chunk
    const u8* gB = Bt + (size_t)(n0 + srow) * K_GLOB + sc * 16;

    // ---- A f32 load + convert map: thread covers 8 dword-pairs.
    // Pair s: row r = s*16 + (tid>>4), floats [ (tid&15)*8 , +8 ) of the
    // kt window. r&7 == (tid>>4)&7 (16 == 0 mod 8) -> constants per thread.
    const int t4 = tid >> 4;         // 0..15
    const int tl = tid & 15;         // 0..15
    const float* gA = A + (size_t)(m0 + t4) * K_GLOB + tl * 8;
    const int zA = t4 & 7;
    const int ldsA_cst = (((tl >> 1) ^ zA) << 4) + (tl & 1) * 8;

    f32x16 acc[2][2];
#pragma unroll
    for (int i = 0; i < 2; ++i)
#pragma unroll
        for (int j = 0; j < 2; ++j)
#pragma unroll
            for (int r = 0; r < 16; ++r)
                acc[i][j][r] = 0.f;

    const int swz = lane & 7;        // fragment row & 7
    const int scale1 = 0x7F7F7F7F;   // e8m0 127 = 2^0 in every byte

    u32x2 sA[8];   // staged fp8 A (dword pairs, one per 16-row stripe)
    u32x4 rb[4];   // staged fp8 B

    // ---- prologue: load + convert tile kt=0
    {
        f32x4 f0[8], f1[8];
#pragma unroll
        for (int s = 0; s < 8; ++s) {
            f0[s] = *(const f32x4*)(gA + (size_t)s * 16 * K_GLOB);
            f1[s] = *(const f32x4*)(gA + (size_t)s * 16 * K_GLOB + 4);
        }
#pragma unroll
        for (int s = 0; s < 8; ++s) {
            sA[s].x = cvt4_fp8(f0[s].x, f0[s].y, f0[s].z, f0[s].w);
            sA[s].y = cvt4_fp8(f1[s].x, f1[s].y, f1[s].z, f1[s].w);
        }
    }
#pragma unroll
    for (int s = 0; s < 4; ++s)
        rb[s] = *(const u32x4*)(gB + (size_t)((s * 4 + wave) * 8) * K_GLOB);

    for (int kt = 0; kt < K_GLOB / BKF; ++kt) {
        // ---- stage current tile (fp8 regs) -> LDS
#pragma unroll
        for (int s = 0; s < 8; ++s)
            *(u32x2*)(smem + (s * 16 + t4) * 128 + ldsA_cst) = sA[s];
#pragma unroll
        for (int s = 0; s < 4; ++s) {
            const int row = (s * 4 + wave) * 8 + srow;
            *(u32x4*)(smem + 16384 + row * 128 + sp * 16) = rb[s];
        }
        __syncthreads();

        // ---- prefetch tile kt+1 (f32 A + fp8 B) into regs; overlaps compute
        f32x4 f0[8], f1[8];
        const bool more = (kt + 1 < K_GLOB / BKF);
        if (more) {
            const size_t k1 = (size_t)(kt + 1) * BKF;   // floats
#pragma unroll
            for (int s = 0; s < 8; ++s) {
                f0[s] = *(const f32x4*)(gA + k1 + (size_t)s * 16 * K_GLOB);
                f1[s] = *(const f32x4*)(gA + k1 + (size_t)s * 16 * K_GLOB + 4);
            }
#pragma unroll
            for (int s = 0; s < 4; ++s)
                rb[s] = *(const u32x4*)(gB + (size_t)((s * 4 + wave) * 8) * K_GLOB + k1);
        }

        // ---- compute on LDS tile (layout identical to proven kernel)
#pragma unroll
        for (int s = 0; s < 2; ++s) {           // two K=64 steps per kt
            const int c0 = s * 4 + half * 2;
            const int p0 = ((c0    ) ^ swz) * 16;
            const int p1 = ((c0 + 1) ^ swz) * 16;
            i32x8 af[2], bf[2];
#pragma unroll
            for (int i = 0; i < 2; ++i) {
                const int row = wr * 64 + i * 32 + l32;
                u32x4 lo = *(const u32x4*)(smem + row * 128 + p0);
                u32x4 hi = *(const u32x4*)(smem + row * 128 + p1);
                af[i][0] = lo.x; af[i][1] = lo.y; af[i][2] = lo.z; af[i][3] = lo.w;
                af[i][4] = hi.x; af[i][5] = hi.y; af[i][6] = hi.z; af[i][7] = hi.w;
            }
#pragma unroll
            for (int j = 0; j < 2; ++j) {
                const int row = wc * 64 + j * 32 + l32;
                u32x4 lo = *(const u32x4*)(smem + 16384 + row * 128 + p0);
                u32x4 hi = *(const u32x4*)(smem + 16384 + row * 128 + p1);
                bf[j][0] = lo.x; bf[j][1] = lo.y; bf[j][2] = lo.z; bf[j][3] = lo.w;
                bf[j][4] = hi.x; bf[j][5] = hi.y; bf[j][6] = hi.z; bf[j][7] = hi.w;
            }
#pragma unroll
            for (int i = 0; i < 2; ++i)
#pragma unroll
                for (int j = 0; j < 2; ++j)
                    acc[i][j] = __builtin_amdgcn_mfma_scale_f32_32x32x64_f8f6f4(
                        af[i], bf[j], acc[i][j],
                        0 /*cbsz: A=fp8 e4m3*/, 0 /*blgp: B=fp8 e4m3*/,
                        0, scale1, 0, scale1);
        }

        // ---- convert the landed prefetch (vmcnt wait lands here, after MFMAs)
        if (more) {
#pragma unroll
            for (int s = 0; s < 8; ++s) {
                sA[s].x = cvt4_fp8(f0[s].x, f0[s].y, f0[s].z, f0[s].w);
                sA[s].y = cvt4_fp8(f1[s].x, f1[s].y, f1[s].z, f1[s].w);
            }
        }
        // End-of-read fence: raw barrier, does NOT drain vmcnt.
        barrier_raw();
    }

    // ---- epilogue: log(max(y,tiny)) staged through LDS in 32-row chunks.
    // 32x32 C/D layout (HW-verified): col=lane&31, row32=(r&3)+8*(r>>2)+4*half.
    const float LN2 = 0.69314718055994530942f;
    const int c4 = tid & 31;
    const int r0 = tid >> 5;
#pragma unroll
    for (int h = 0; h < 4; ++h) {
        __syncthreads();
        if (wr == (h >> 1)) {
            const int i = h & 1;
#pragma unroll
            for (int j = 0; j < 2; ++j) {
                const int col = wc * 64 + j * 32 + l32;
#pragma unroll
                for (int r = 0; r < 16; ++r) {
                    const int row32 = (r & 3) + 8 * (r >> 2) + 4 * half;
                    float v = fmaxf(acc[i][j][r], 1.17549435e-38f);
                    Cs[row32 * 132 + col] = __log2f(v) * LN2;
                }
            }
        }
        __syncthreads();
#pragma unroll
        for (int s2 = 0; s2 < 4; ++s2) {
            const int row = s2 * 8 + r0;
            f32x4 v = *(const f32x4*)&Cs[row * 132 + c4 * 4];
            __builtin_nontemporal_store(v,
                (f32x4*)&C[(size_t)(m0 + h * 32 + row) * N_GLOB + n0 + c4 * 4]);
        }
    }
}

// ---------------------------------------------------------------------------
// Fallback (round-1 kernel): fused fp32->bf16 staging, padded LDS.
// Used only if ws can't hold Bt (1 MiB).
// ---------------------------------------------------------------------------
#define FBM 128
#define FBN 128
#define LDK 40
__global__ __launch_bounds__(256)
void logmm_fused_kernel(const float* __restrict__ A,
                        const float* __restrict__ Bf,
                        float* __restrict__ C)
{
    __shared__ u16 As[FBM][LDK];
    __shared__ u16 Bs[FBN][LDK];

    const int tid  = threadIdx.x;
    const int lane = tid & 63;
    const int wave = tid >> 6;
    const int wr   = wave >> 1;
    const int wc   = wave & 1;
    const int quad = lane >> 4;
    const int l16  = lane & 15;

    const int m0 = blockIdx.y * FBM;
    const int n0 = blockIdx.x * FBN;

    f32x4 acc[4][4];
#pragma unroll
    for (int i = 0; i < 4; ++i)
#pragma unroll
        for (int j = 0; j < 4; ++j)
            acc[i][j] = f32x4{0.f, 0.f, 0.f, 0.f};

    const int ga_row = tid >> 2;
    const int ga_c8  = (tid & 3) * 8;
    const int fb_nt = tid >> 3;
    const int fb_kt = tid & 7;

    for (int kt = 0; kt < K_GLOB / 32; ++kt) {
        const int k0 = kt * 32;
#pragma unroll
        for (int s = 0; s < 2; ++s) {
            const int row = ga_row + s * 64;
            const float* src = A + (size_t)(m0 + row) * K_GLOB + k0 + ga_c8;
            f32x4 f0 = *(const f32x4*)src;
            f32x4 f1 = *(const f32x4*)(src + 4);
            u32x4 o;
            o.x = pack2_bf16(f0.x, f0.y);
            o.y = pack2_bf16(f0.z, f0.w);
            o.z = pack2_bf16(f1.x, f1.y);
            o.w = pack2_bf16(f1.z, f1.w);
            *(u32x4*)&As[row][ga_c8] = o;
        }
        {
            f32x4 r0 = *(const f32x4*)(Bf + (size_t)(k0 + fb_kt * 4 + 0) * N_GLOB + n0 + fb_nt * 4);
            f32x4 r1 = *(const f32x4*)(Bf + (size_t)(k0 + fb_kt * 4 + 1) * N_GLOB + n0 + fb_nt * 4);
            f32x4 r2 = *(const f32x4*)(Bf + (size_t)(k0 + fb_kt * 4 + 2) * N_GLOB + n0 + fb_nt * 4);
            f32x4 r3 = *(const f32x4*)(Bf + (size_t)(k0 + fb_kt * 4 + 3) * N_GLOB + n0 + fb_nt * 4);
#pragma unroll
            for (int j = 0; j < 4; ++j) {
                u32x2 o;
                o.x = pack2_bf16(r0[j], r1[j]);
                o.y = pack2_bf16(r2[j], r3[j]);
                *(u32x2*)&Bs[fb_nt * 4 + j][fb_kt * 4] = o;
            }
        }

        __syncthreads();

        bf16x8 af[4], bfr[4];
#pragma unroll
        for (int i = 0; i < 4; ++i)
            af[i] = __builtin_bit_cast(bf16x8, *(const u32x4*)&As[wr * 64 + i * 16 + l16][quad * 8]);
#pragma unroll
        for (int j = 0; j < 4; ++j)
            bfr[j] = __builtin_bit_cast(bf16x8, *(const u32x4*)&Bs[wc * 64 + j * 16 + l16][quad * 8]);

#pragma unroll
        for (int i = 0; i < 4; ++i)
#pragma unroll
            for (int j = 0; j < 4; ++j)
                acc[i][j] = __builtin_amdgcn_mfma_f32_16x16x32_bf16(af[i], bfr[j], acc[i][j], 0, 0, 0);

        __syncthreads();
    }

    const float LN2 = 0.69314718055994530942f;
#pragma unroll
    for (int i = 0; i < 4; ++i) {
#pragma unroll
        for (int j = 0; j < 4; ++j) {
            const int col = n0 + wc * 64 + j * 16 + l16;
#pragma unroll
            for (int r = 0; r < 4; ++r) {
                const int row = m0 + wr * 64 + i * 16 + quad * 4 + r;
                float v = fmaxf(acc[i][j][r], 1.17549435e-38f);
                C[(size_t)row * N_GLOB + col] = __log2f(v) * LN2;
            }
        }
    }
}

extern "C" void kernel_launch(void* const* d_in, const int* in_sizes, int n_in,
                              void* d_out, int out_size, void* d_ws, size_t ws_size,
                              hipStream_t stream) {
    const float* A = (const float*)d_in[0];   // x: [16384,1024]
    const float* B = (const float*)d_in[1];   // matrix: [1024,1024]
    float* C = (float*)d_out;

    const size_t bt_bytes = (size_t)N_GLOB * K_GLOB;        // 1 MiB fp8

    if (ws_size >= bt_bytes) {
        u8* Bt = (u8*)d_ws;
        prep_b_kernel<<<1024, 256, 0, stream>>>(B, Bt);
        gemm_fused_kernel<<<(M_GLOB / BM) * (N_GLOB / BN), 256, 0, stream>>>(A, Bt, C);
    } else {
        logmm_fused_kernel<<<dim3(N_GLOB / FBN, M_GLOB / FBM), 256, 0, stream>>>(A, B, C);
    }
}

// Round 2
// 132.543 us; speedup vs baseline: 1.1711x; 1.1711x over previous
//
#include <hip/hip_runtime.h>
#include <cstdint>
#include <cstddef>

// LogMM_19490561589867: x [8,2048,1024] f32, matrix [1024,1024] f32
// out = log(max(x @ matrix, tiny))  [8,2048,1024] f32
// Round-9: REVERT the f32-A fusion (measured: 67.6us GEMM, 9% MfmaUtil,
// 512MB L2-side A traffic, vmcnt-gated cvt chain). Back to two-kernel fp8
// structure (round-0, 132us), with the GEMM staging switched from VGPR
// reg-staging to global_load_lds width-16 (m151: 874 vs 646 TF at 128^2).
// Our LDS map is linear-in-lane (offset == 16*lane) with the XOR swizzle
// applied on the GLOBAL source address -> gload_lds is a drop-in.
// Tile 128x128, 32KB LDS, acc 64 VGPR -> 3 blocks/CU for drain overlap.
// Numerics identical: fp8 e4m3 RNE quantized GEMM, absmax 0.03125 (floor).
#define M_GLOB 16384
#define N_GLOB 1024
#define K_GLOB 1024

#define BM 128    // block tile rows
#define BN 128    // block tile cols
#define BKF 128   // fp8 K-tile bytes: 2 MX K=64 steps per kt, 8 kt total

typedef unsigned char  u8;
typedef unsigned short u16;
typedef __attribute__((ext_vector_type(4))) float  f32x4;
typedef __attribute__((ext_vector_type(16))) float f32x16;
typedef __attribute__((ext_vector_type(4))) unsigned int  u32x4;
typedef __attribute__((ext_vector_type(2))) unsigned int  u32x2;
typedef __attribute__((ext_vector_type(8))) int  i32x8;
typedef __attribute__((ext_vector_type(8))) __bf16 bf16x8;

// truncating pack (fallback fused path — round-1 proven numerics)
static __device__ __forceinline__ unsigned pack2_bf16(float lo, float hi) {
    unsigned bl = __builtin_bit_cast(unsigned, lo);
    unsigned bh = __builtin_bit_cast(unsigned, hi);
    return (bh & 0xFFFF0000u) | (bl >> 16);
}

// 4 fp32 -> 4 fp8 e4m3 bytes (HW RNE, OCP on gfx950)
static __device__ __forceinline__ unsigned cvt4_fp8(float a, float b, float c, float d) {
    int w = __builtin_amdgcn_cvt_pk_fp8_f32(a, b, 0, false);
    w = __builtin_amdgcn_cvt_pk_fp8_f32(c, d, w, true);
    return (unsigned)w;
}

// Async global->LDS DMA, 16 B per lane. LDS dest is wave-uniform base
// (HW adds lane*16); global src is per-lane (pre-swizzled). Tracked by vmcnt;
// __syncthreads() drains it (m97 pattern).
static __device__ __forceinline__ void gload_lds16(const u8* g, char* l) {
    __builtin_amdgcn_global_load_lds(
        (const __attribute__((address_space(1))) unsigned int*)g,
        (__attribute__((address_space(3))) unsigned int*)l,
        16, 0, 0);
}

// ---------------------------------------------------------------------------
// Prep (merged, round-0 proven): blocks [0,nA): Ab = e4m3(A), 16 f/thread.
//                blocks [nA, nA+1024): Bt[n][k] = e4m3(B[k][n]), 32x32 tiles.
// ---------------------------------------------------------------------------
__global__ __launch_bounds__(256)
void prep_fp8_kernel(const float* __restrict__ A, u8* __restrict__ Ab,
                     const float* __restrict__ B, u8* __restrict__ Bt, int nA) {
    __shared__ float tile[32][33];
    const int tid = threadIdx.x;
    if ((int)blockIdx.x < nA) {
        const size_t i = ((size_t)blockIdx.x * 256 + tid) * 16;
        f32x4 f0 = *(const f32x4*)(A + i);
        f32x4 f1 = *(const f32x4*)(A + i + 4);
        f32x4 f2 = *(const f32x4*)(A + i + 8);
        f32x4 f3 = *(const f32x4*)(A + i + 12);
        u32x4 o;
        o.x = cvt4_fp8(f0.x, f0.y, f0.z, f0.w);
        o.y = cvt4_fp8(f1.x, f1.y, f1.z, f1.w);
        o.z = cvt4_fp8(f2.x, f2.y, f2.z, f2.w);
        o.w = cvt4_fp8(f3.x, f3.y, f3.z, f3.w);
        *(u32x4*)(Ab + i) = o;
    } else {
        const int bid = (int)blockIdx.x - nA;
        const int n0 = (bid & 31) * 32;
        const int k0 = (bid >> 5) * 32;
        const int tx = tid & 31;
        const int ty = tid >> 5;   // 0..7
#pragma unroll
        for (int i = 0; i < 32; i += 8)
            tile[ty + i][tx] = B[(size_t)(k0 + ty + i) * N_GLOB + n0 + tx];
        __syncthreads();
#pragma unroll
        for (int i = 0; i < 32; i += 8) {
            int w = __builtin_amdgcn_cvt_pk_fp8_f32(tile[tx][ty + i], 0.f, 0, false);
            Bt[(size_t)(n0 + ty + i) * K_GLOB + k0 + tx] = (u8)(w & 0xFF);
        }
    }
}

// ---------------------------------------------------------------------------
// Main GEMM (MX-scaled fp8, unit scales): Ab [M][K] fp8, Bt [N][K] fp8 -> C.
//  - mfma_scale_f32_32x32x64_f8f6f4, scales 0x7F (=1.0): pure fp8 at 2x rate.
//  - Block 128x128; wave tile 64x64 = 2x2 of 32x32 (acc 64 VGPR).
//  - Staging: global_load_lds width 16 (m97/m151: best at 128^2 tiles).
//    LDS dest linear-in-lane (16*lane within each wave's 1KB stripe);
//    XOR swizzle pre-applied on the GLOBAL source chunk (sc = sp ^ srow),
//    so LDS position p of row r holds global chunk p ^ (r&7) — identical
//    invariant to the round-3 measured zero-conflict layout.
//  - 2-barrier loop: stage -> sync (vmcnt drain) -> compute -> sync.
//    Drain stall hidden by 3 resident blocks/CU (32KB LDS, ~130 VGPR).
//  - Epilogue: 4 chunks of 32 rows staged via LDS (stride 132) ->
//    coalesced nontemporal f32x4 stores (proven WRITE_SIZE == ideal).
// ---------------------------------------------------------------------------
__global__ __launch_bounds__(256, 3)
void gemm_mx_kernel(const u8* __restrict__ A,
                    const u8* __restrict__ Bt,
                    float* __restrict__ C)
{
    // As: 128x128 fp8 = 16 KB @0 ; Bs: 128x128 fp8 = 16 KB @16384.
    // Epilogue reuses first 16896 B as Cs (32 rows x 132 f32).
    __shared__ __attribute__((aligned(16))) char smem[32768];
    float* Cs = (float*)smem;

    const int tid  = threadIdx.x;
    const int wave = tid >> 6;
    const int lane = tid & 63;
    const int wr   = wave >> 1;     // wave row: 64 rows each
    const int wc   = wave & 1;      // wave col: 64 cols each
    const int l32  = lane & 31;
    const int half = lane >> 5;     // k-half selector of the MFMA operand

    // XCD-contiguous swizzle: 8 blocks sharing an A panel land on one XCD.
    const int b    = (int)blockIdx.x;     // 0..1023
    const int xcd  = b & 7;
    const int idx  = b >> 3;              // 0..127
    const int m0   = (xcd * 16 + (idx >> 3)) * BM;
    const int n0   = (idx & 7) * BN;

    // Staging map: slot s covers 8 rows. Lane L -> row (L>>3), LDS chunk
    // position p = L&7 holding global chunk c = p ^ (L>>3).
    const int srow = lane >> 3;                  // 0..7
    const int sp   = lane & 7;                   // LDS chunk position
    const int sc   = sp ^ srow;                  // swizzled global 16B chunk
    const u8* gA = A  + (size_t)(m0 + srow) * K_GLOB + sc * 16;
    const u8* gB = Bt + (size_t)(n0 + srow) * K_GLOB + sc * 16;
    // Wave-uniform LDS bases: slot s stripe = (s*4+wave)*8 rows * 128 B.
    char* ldsA = smem + wave * 1024;
    char* ldsB = smem + 16384 + wave * 1024;

    f32x16 acc[2][2];
#pragma unroll
    for (int i = 0; i < 2; ++i)
#pragma unroll
        for (int j = 0; j < 2; ++j)
#pragma unroll
            for (int r = 0; r < 16; ++r)
                acc[i][j][r] = 0.f;

    const int swz = lane & 7;        // fragment row & 7
    const int scale1 = 0x7F7F7F7F;   // e8m0 127 = 2^0 in every byte

    for (int kt = 0; kt < K_GLOB / BKF; ++kt) {
        const int ko = kt * BKF;
        // ---- stage tile kt via async DMA (4 A + 4 B issues per thread)
#pragma unroll
        for (int s = 0; s < 4; ++s)
            gload_lds16(gA + (size_t)(s * 4 + wave) * 8 * K_GLOB + ko,
                        ldsA + s * 4096);
#pragma unroll
        for (int s = 0; s < 4; ++s)
            gload_lds16(gB + (size_t)(s * 4 + wave) * 8 * K_GLOB + ko,
                        ldsB + s * 4096);
        __syncthreads();   // drains vmcnt: LDS tile ready for all waves

        // ---- compute on LDS tile (identical frag layout to proven kernel)
#pragma unroll
        for (int s = 0; s < 2; ++s) {           // two K=64 steps per kt
            const int c0 = s * 4 + half * 2;
            const int p0 = ((c0    ) ^ swz) * 16;
            const int p1 = ((c0 + 1) ^ swz) * 16;
            i32x8 af[2], bf[2];
#pragma unroll
            for (int i = 0; i < 2; ++i) {
                const int row = wr * 64 + i * 32 + l32;
                u32x4 lo = *(const u32x4*)(smem + row * 128 + p0);
                u32x4 hi = *(const u32x4*)(smem + row * 128 + p1);
                af[i][0] = lo.x; af[i][1] = lo.y; af[i][2] = lo.z; af[i][3] = lo.w;
                af[i][4] = hi.x; af[i][5] = hi.y; af[i][6] = hi.z; af[i][7] = hi.w;
            }
#pragma unroll
            for (int j = 0; j < 2; ++j) {
                const int row = wc * 64 + j * 32 + l32;
                u32x4 lo = *(const u32x4*)(smem + 16384 + row * 128 + p0);
                u32x4 hi = *(const u32x4*)(smem + 16384 + row * 128 + p1);
                bf[j][0] = lo.x; bf[j][1] = lo.y; bf[j][2] = lo.z; bf[j][3] = lo.w;
                bf[j][4] = hi.x; bf[j][5] = hi.y; bf[j][6] = hi.z; bf[j][7] = hi.w;
            }
#pragma unroll
            for (int i = 0; i < 2; ++i)
#pragma unroll
                for (int j = 0; j < 2; ++j)
                    acc[i][j] = __builtin_amdgcn_mfma_scale_f32_32x32x64_f8f6f4(
                        af[i], bf[j], acc[i][j],
                        0 /*cbsz: A=fp8 e4m3*/, 0 /*blgp: B=fp8 e4m3*/,
                        0, scale1, 0, scale1);
        }
        __syncthreads();   // all reads done before next stage overwrites
    }

    // ---- epilogue: log(max(y,tiny)) staged through LDS in 32-row chunks.
    // 32x32 C/D layout (HW-verified): col=lane&31, row32=(r&3)+8*(r>>2)+4*half.
    const float LN2 = 0.69314718055994530942f;
    const int c4 = tid & 31;
    const int r0 = tid >> 5;
#pragma unroll
    for (int h = 0; h < 4; ++h) {
        __syncthreads();
        if (wr == (h >> 1)) {
            const int i = h & 1;
#pragma unroll
            for (int j = 0; j < 2; ++j) {
                const int col = wc * 64 + j * 32 + l32;
#pragma unroll
                for (int r = 0; r < 16; ++r) {
                    const int row32 = (r & 3) + 8 * (r >> 2) + 4 * half;
                    float v = fmaxf(acc[i][j][r], 1.17549435e-38f);
                    Cs[row32 * 132 + col] = __log2f(v) * LN2;
                }
            }
        }
        __syncthreads();
#pragma unroll
        for (int s2 = 0; s2 < 4; ++s2) {
            const int row = s2 * 8 + r0;
            f32x4 v = *(const f32x4*)&Cs[row * 132 + c4 * 4];
            __builtin_nontemporal_store(v,
                (f32x4*)&C[(size_t)(m0 + h * 32 + row) * N_GLOB + n0 + c4 * 4]);
        }
    }
}

// ---------------------------------------------------------------------------
// Fallback (round-1 kernel): fused fp32->bf16 staging, padded LDS.
// Used only if ws can't hold the fp8 buffers (17 MiB).
// ---------------------------------------------------------------------------
#define FBM 128
#define FBN 128
#define LDK 40
__global__ __launch_bounds__(256)
void logmm_fused_kernel(const float* __restrict__ A,
                        const float* __restrict__ Bf,
                        float* __restrict__ C)
{
    __shared__ u16 As[FBM][LDK];
    __shared__ u16 Bs[FBN][LDK];

    const int tid  = threadIdx.x;
    const int lane = tid & 63;
    const int wave = tid >> 6;
    const int wr   = wave >> 1;
    const int wc   = wave & 1;
    const int quad = lane >> 4;
    const int l16  = lane & 15;

    const int m0 = blockIdx.y * FBM;
    const int n0 = blockIdx.x * FBN;

    f32x4 acc[4][4];
#pragma unroll
    for (int i = 0; i < 4; ++i)
#pragma unroll
        for (int j = 0; j < 4; ++j)
            acc[i][j] = f32x4{0.f, 0.f, 0.f, 0.f};

    const int ga_row = tid >> 2;
    const int ga_c8  = (tid & 3) * 8;
    const int fb_nt = tid >> 3;
    const int fb_kt = tid & 7;

    for (int kt = 0; kt < K_GLOB / 32; ++kt) {
        const int k0 = kt * 32;
#pragma unroll
        for (int s = 0; s < 2; ++s) {
            const int row = ga_row + s * 64;
            const float* src = A + (size_t)(m0 + row) * K_GLOB + k0 + ga_c8;
            f32x4 f0 = *(const f32x4*)src;
            f32x4 f1 = *(const f32x4*)(src + 4);
            u32x4 o;
            o.x = pack2_bf16(f0.x, f0.y);
            o.y = pack2_bf16(f0.z, f0.w);
            o.z = pack2_bf16(f1.x, f1.y);
            o.w = pack2_bf16(f1.z, f1.w);
            *(u32x4*)&As[row][ga_c8] = o;
        }
        {
            f32x4 r0 = *(const f32x4*)(Bf + (size_t)(k0 + fb_kt * 4 + 0) * N_GLOB + n0 + fb_nt * 4);
            f32x4 r1 = *(const f32x4*)(Bf + (size_t)(k0 + fb_kt * 4 + 1) * N_GLOB + n0 + fb_nt * 4);
            f32x4 r2 = *(const f32x4*)(Bf + (size_t)(k0 + fb_kt * 4 + 2) * N_GLOB + n0 + fb_nt * 4);
            f32x4 r3 = *(const f32x4*)(Bf + (size_t)(k0 + fb_kt * 4 + 3) * N_GLOB + n0 + fb_nt * 4);
#pragma unroll
            for (int j = 0; j < 4; ++j) {
                u32x2 o;
                o.x = pack2_bf16(r0[j], r1[j]);
                o.y = pack2_bf16(r2[j], r3[j]);
                *(u32x2*)&Bs[fb_nt * 4 + j][fb_kt * 4] = o;
            }
        }

        __syncthreads();

        bf16x8 af[4], bfr[4];
#pragma unroll
        for (int i = 0; i < 4; ++i)
            af[i] = __builtin_bit_cast(bf16x8, *(const u32x4*)&As[wr * 64 + i * 16 + l16][quad * 8]);
#pragma unroll
        for (int j = 0; j < 4; ++j)
            bfr[j] = __builtin_bit_cast(bf16x8, *(const u32x4*)&Bs[wc * 64 + j * 16 + l16][quad * 8]);

#pragma unroll
        for (int i = 0; i < 4; ++i)
#pragma unroll
            for (int j = 0; j < 4; ++j)
                acc[i][j] = __builtin_amdgcn_mfma_f32_16x16x32_bf16(af[i], bfr[j], acc[i][j], 0, 0, 0);

        __syncthreads();
    }

    const float LN2 = 0.69314718055994530942f;
#pragma unroll
    for (int i = 0; i < 4; ++i) {
#pragma unroll
        for (int j = 0; j < 4; ++j) {
            const int col = n0 + wc * 64 + j * 16 + l16;
#pragma unroll
            for (int r = 0; r < 4; ++r) {
                const int row = m0 + wr * 64 + i * 16 + quad * 4 + r;
                float v = fmaxf(acc[i][j][r], 1.17549435e-38f);
                C[(size_t)row * N_GLOB + col] = __log2f(v) * LN2;
            }
        }
    }
}

extern "C" void kernel_launch(void* const* d_in, const int* in_sizes, int n_in,
                              void* d_out, int out_size, void* d_ws, size_t ws_size,
                              hipStream_t stream) {
    const float* A = (const float*)d_in[0];   // x: [16384,1024]
    const float* B = (const float*)d_in[1];   // matrix: [1024,1024]
    float* C = (float*)d_out;

    const size_t bt_bytes = (size_t)N_GLOB * K_GLOB;        // 1 MiB fp8
    const size_t ab_bytes = (size_t)M_GLOB * K_GLOB;        // 16 MiB fp8
    const int nA = (M_GLOB * K_GLOB) / (256 * 16);          // 4096 cvt blocks

    if (ws_size >= bt_bytes + ab_bytes) {
        u8* Bt = (u8*)d_ws;
        u8* Ab = (u8*)d_ws + bt_bytes;
        prep_fp8_kernel<<<nA + 1024, 256, 0, stream>>>(A, Ab, B, Bt, nA);
        gemm_mx_kernel<<<(M_GLOB / BM) * (N_GLOB / BN), 256, 0, stream>>>(Ab, Bt, C);
    } else {
        logmm_fused_kernel<<<dim3(N_GLOB / FBN, M_GLOB / FBM), 256, 0, stream>>>(A, B, C);
    }
}